// Round 5
// baseline (275.164 us; speedup 1.0000x reference)
//
#include <hip/hip_runtime.h>

typedef unsigned int  uint;
typedef unsigned short u16;
typedef __attribute__((ext_vector_type(8))) short bf16x8;   // 8 bf16 in 4 VGPRs
typedef __attribute__((ext_vector_type(4))) float f32x4;

// ---- d_ws weight-fragment offsets (u16 units) ----
#define OF_W1B   0
#define OF_W1C   4096
#define OF_TA2   8192
#define OF_TB2   12288
#define OF_W1    16384
#define OF_TA1   18432
#define OF_TB1   20480
#define OF_W2AB  22528
#define WTOT     23552
// ---- bias offsets (f32 units, region starts at WS + WTOT u16) ----
#define BTA2 0
#define BTB2 64
#define BB1B 128
#define BB1C 192
#define BH   256   // [0..7]=b2a, [8]=b2b, [9..15]=0
#define BIASN 272

#if defined(__has_builtin) && __has_builtin(__builtin_amdgcn_exp2f)
#define EXP2F(x) __builtin_amdgcn_exp2f(x)
#else
#define EXP2F(x) __expf((x) * 0.6931471805599453f)
#endif
#if defined(__has_builtin) && __has_builtin(__builtin_amdgcn_rcpf)
#define RCPF(x) __builtin_amdgcn_rcpf(x)
#else
#define RCPF(x) __fdividef(1.0f, (x))
#endif

// tanh = 1 - 2/(exp2(x*2*log2e)+1): 3 VALU + 2 trans
__device__ __forceinline__ float ftanh(float x){
    const float e = EXP2F(x * 2.8853900817779268f);
    return __builtin_fmaf(-2.0f, RCPF(e + 1.0f), 1.0f);
}
__device__ __forceinline__ float fsigm(float x){
    return RCPF(1.0f + EXP2F(-1.4426950408889634f * x));
}
// pack 2 f32 -> 2 bf16 (RNE), 1 instruction
__device__ __forceinline__ uint cvtpk(float lo, float hi){
    uint r; asm("v_cvt_pk_bf16_f32 %0, %1, %2" : "=v"(r) : "v"(lo), "v"(hi)); return r;
}
__device__ __forceinline__ u16 bfb(float x){    // prep-kernel scalar pack
    union { float f; uint u; } v; v.f = x;
    return (u16)((v.u + 0x7fffu + ((v.u >> 16) & 1u)) >> 16);
}
__device__ __forceinline__ f32x4 MFMA(bf16x8 a, bf16x8 b, f32x4 c){
    return __builtin_amdgcn_mfma_f32_16x16x32_bf16(a, b, c, 0, 0, 0);
}

__device__ __forceinline__ void zacc(f32x4 (&acc)[4][4]){
    #pragma unroll
    for (int mt = 0; mt < 4; ++mt)
        #pragma unroll
        for (int n = 0; n < 4; ++n) acc[mt][n] = f32x4{0.f, 0.f, 0.f, 0.f};
}
__device__ __forceinline__ void ld_bias(const float* __restrict__ WB, int bb, int q,
                                        f32x4 (&acc)[4][4]){
    #pragma unroll
    for (int mt = 0; mt < 4; ++mt){
        const f32x4 b4 = *(const f32x4*)&WB[bb + 16*mt + 4*q];
        #pragma unroll
        for (int n = 0; n < 4; ++n) acc[mt][n] = b4;
    }
}

// ---- layers: Ab = &WS[lane*8] (GLOBAL, L1-hot), Bb = &ACT_wave[lane*8] (LDS) ----
__device__ __forceinline__ void layer_k32(const u16* __restrict__ Ab, const u16* Bb, int WB,
                                          f32x4 (&acc)[4][4]){
    bf16x8 A[4];
    #pragma unroll
    for (int mt = 0; mt < 4; ++mt) A[mt] = *(const bf16x8*)&Ab[WB + mt*512];
    #pragma unroll
    for (int n = 0; n < 4; ++n){
        const bf16x8 B = *(const bf16x8*)&Bb[n*1024];
        #pragma unroll
        for (int mt = 0; mt < 4; ++mt) acc[mt][n] = MFMA(A[mt], B, acc[mt][n]);
    }
}
__device__ __forceinline__ void layer_k64(const u16* __restrict__ Ab, const u16* Bb, int WB,
                                          f32x4 (&acc)[4][4]){
    #pragma unroll
    for (int s = 0; s < 2; ++s){          // s-outer: only 4 A-frags (16 VGPR) live
        bf16x8 A[4];
        #pragma unroll
        for (int mt = 0; mt < 4; ++mt) A[mt] = *(const bf16x8*)&Ab[WB + (mt*2+s)*512];
        #pragma unroll
        for (int n = 0; n < 4; ++n){
            const bf16x8 B = *(const bf16x8*)&Bb[n*1024 + s*512];
            #pragma unroll
            for (int mt = 0; mt < 4; ++mt) acc[mt][n] = MFMA(A[mt], B, acc[mt][n]);
        }
    }
}
__device__ __forceinline__ void head_k64(const u16* __restrict__ Ab, const u16* Bb,
                                         f32x4 (&ah)[4]){
    const bf16x8 A0 = *(const bf16x8*)&Ab[OF_W2AB];
    const bf16x8 A1 = *(const bf16x8*)&Ab[OF_W2AB + 512];
    #pragma unroll
    for (int n = 0; n < 4; ++n){
        const bf16x8 B0 = *(const bf16x8*)&Bb[n*1024];
        const bf16x8 B1 = *(const bf16x8*)&Bb[n*1024 + 512];
        ah[n] = MFMA(A0, B0, ah[n]);
        ah[n] = MFMA(A1, B1, ah[n]);
    }
}

// D-epilogue store: lane holds rows j=16mt+4q+c of col b=16n+(lane&15); dest = B-frag slot
__device__ __forceinline__ void stD(u16* EW, int mt, int n, uint lo, uint hi){
    *(uint2*)&EW[(n*2 + (mt>>1))*512 + (mt&1)*256] = make_uint2(lo, hi);
}
__device__ __forceinline__ void epi_tanh(u16* EW, const f32x4 (&acc)[4][4]){
    #pragma unroll
    for (int mt = 0; mt < 4; ++mt)
        #pragma unroll
        for (int n = 0; n < 4; ++n)
            stD(EW, mt, n, cvtpk(ftanh(acc[mt][n][0]), ftanh(acc[mt][n][1])),
                           cvtpk(ftanh(acc[mt][n][2]), ftanh(acc[mt][n][3])));
}

// input row write: lane's own row, k=0..31 (k31 = 1.0 -> bias-in-k31)
template<int NR>
__device__ __forceinline__ void write_xrow(u16* XW, const float (&x)[NR]){
    uint buf[16];
    #pragma unroll
    for (int i = 0; i < 16; ++i){
        if (2*i < NR){
            const float lo = x[2*i];
            const float hi = (2*i+1 < NR) ? x[2*i+1] : 0.f;
            buf[i] = cvtpk(lo, hi);
        } else buf[i] = 0u;
    }
    buf[15] = 0x3F800000u;   // k30=0, k31=bf16(1.0)
    #pragma unroll
    for (int kb = 0; kb < 4; ++kb)
        *(uint4*)&XW[kb*128] = make_uint4(buf[4*kb], buf[4*kb+1], buf[4*kb+2], buf[4*kb+3]);
}

// =================== prep kernel: weights -> fragment layout in d_ws ===================
__global__ __launch_bounds__(256)
void prep_weights(const float* __restrict__ W1,  const float* __restrict__ b1,
                  const float* __restrict__ W1b, const float* __restrict__ b1b,
                  const float* __restrict__ W1c, const float* __restrict__ b1c,
                  const float* __restrict__ W2a, const float* __restrict__ b2a,
                  const float* __restrict__ W2b, const float* __restrict__ b2b,
                  const float* __restrict__ Ta1, const float* __restrict__ ta1,
                  const float* __restrict__ Ta2, const float* __restrict__ ta2,
                  const float* __restrict__ Tb1, const float* __restrict__ tb1,
                  const float* __restrict__ Tb2, const float* __restrict__ tb2,
                  u16* __restrict__ WS)
{
    const int b = blockIdx.x, tid = threadIdx.x;
    if (b < 4){
        const float* Wg = (b==0) ? W1b : (b==1) ? W1c : (b==2) ? Ta2 : Tb2;
        const int    bb = (b==0) ? OF_W1B : (b==1) ? OF_W1C : (b==2) ? OF_TA2 : OF_TB2;
        #pragma unroll 1
        for (int idx = tid; idx < 4096; idx += 256){
            const int k = idx >> 6, j = idx & 63;   // A[j][k] = W[k][j]
            WS[bb + (((j>>4)<<1)|(k>>5))*512 + ((j&15)|(((k>>3)&3)<<4))*8 + (k&7)] = bfb(Wg[idx]);
        }
        return;
    }
    // ---- block 4: zero pads, small matrices, k31 bias rows, f32 bias table ----
    float* WB = (float*)(WS + WTOT);
    #pragma unroll 1
    for (int i = tid; i < (WTOT - OF_W1); i += 256) WS[OF_W1 + i] = 0;
    __syncthreads();
    #pragma unroll 1
    for (int idx = tid; idx < 896; idx += 256){          // W1: 14x64
        const int k = idx >> 6, j = idx & 63;
        WS[OF_W1 + (j>>4)*512 + ((j&15)|(((k>>3)&3)<<4))*8 + (k&7)] = bfb(W1[idx]);
    }
    #pragma unroll 1
    for (int idx = tid; idx < 320; idx += 256){          // Ta1 / Tb1: 5x64
        const int k = idx >> 6, j = idx & 63;
        const int d = (j>>4)*512 + ((j&15)|(((k>>3)&3)<<4))*8 + (k&7);
        WS[OF_TA1 + d] = bfb(Ta1[idx]);
        WS[OF_TB1 + d] = bfb(Tb1[idx]);
    }
    #pragma unroll 1
    for (int idx = tid; idx < 512; idx += 256){          // W2a: m=i(0..7), k=j
        const int j = idx >> 3, i = idx & 7;
        WS[OF_W2AB + (j>>5)*512 + (i|(((j>>3)&3)<<4))*8 + (j&7)] = bfb(W2a[idx]);
    }
    if (tid < 64){
        const int j = tid;
        WS[OF_W2AB + (j>>5)*512 + (8|(((j>>3)&3)<<4))*8 + (j&7)] = bfb(W2b[j]); // m=8 row
        const int d31 = ((j&15)|(3<<4))*8 + 7;           // k=31 bias rows
        WS[OF_W1  + (j>>4)*512 + d31] = bfb(b1[j]);
        WS[OF_TA1 + (j>>4)*512 + d31] = bfb(ta1[j]);
        WS[OF_TB1 + (j>>4)*512 + d31] = bfb(tb1[j]);
        WB[BTA2+j] = ta2[j]; WB[BTB2+j] = tb2[j];
        WB[BB1B+j] = b1b[j]; WB[BB1C+j] = b1c[j];
    }
    if (tid < 16) WB[BH+tid] = (tid < 8) ? b2a[tid] : (tid == 8 ? b2b[0] : 0.0f);
}

// =================== main kernel ===================
// waves_per_eu(4,4): PIN exactly 4 waves/EU -> VGPR cap 128 (R3 proved the body
// fits in 128 with ~9MB spill). R4's (4) was a MINIMUM -> allocator chased 8
// waves/EU, capped VGPR at 64, spilled 265MB. Never leave the max unset.
__global__ __launch_bounds__(256)
__attribute__((amdgpu_waves_per_eu(4, 4)))
void net_mfma(const float* __restrict__ states, const float* __restrict__ action,
              const float* __restrict__ b_type, const float* __restrict__ table,
              const u16* __restrict__ WS, int Btot, float* __restrict__ out)
{
    __shared__ u16 ACT[4*4096];        // 32 KB: per-wave [tile n][sub s][lane][8] bf16

    const int tid  = threadIdx.x;
    const int lane = tid & 63;
    const int q    = lane >> 4;
    const int wv   = tid >> 6;
    u16* ACW = &ACT[wv << 12];
    const u16*   Ab = &WS[lane*8];                 // global, L1-hot
    const float* WB = (const float*)(WS + WTOT);   // f32 bias table
    const u16* Bb = &ACW[lane*8];
    u16* XW = &ACW[(lane>>4)*1024 + (lane&15)*8];
    u16* EW = &ACW[(q>>1)*128 + (lane&15)*8 + 4*(q&1)];

    const int ebw   = blockIdx.x*256 + wv*64;
    const int elast = Btot - 1;
    const int eme   = min(ebw + lane, elast);

    float a8[8];
    { const float* ap = action + (size_t)eme*8;
      const float4 a0 = *(const float4*)ap; const float4 a1 = *(const float4*)(ap+4);
      a8[0]=a0.x; a8[1]=a0.y; a8[2]=a0.z; a8[3]=a0.w; a8[4]=a1.x; a8[5]=a1.y; a8[6]=a1.z; a8[7]=a1.w; }
    const float* sp = states + (size_t)eme*54;

    // ---------------- gate1, packed bf16 in regs ----------------
    uint2 gp[4][4];
    {
        float x5[5];
        { const float* bp = b_type + (size_t)eme*5;
          #pragma unroll
          for (int k = 0; k < 5; ++k) x5[k] = bp[k]; }
        write_xrow<5>(XW, x5);
        f32x4 acc[4][4];
        zacc(acc);
        layer_k32(Ab, Bb, OF_TA1, acc);
        epi_tanh(EW, acc);
        ld_bias(WB, BTA2, q, acc);
        layer_k64(Ab, Bb, OF_TA2, acc);
        #pragma unroll
        for (int mt = 0; mt < 4; ++mt)
            #pragma unroll
            for (int n = 0; n < 4; ++n)
                gp[mt][n] = make_uint2(cvtpk(ftanh(acc[mt][n][0]), ftanh(acc[mt][n][1])),
                                       cvtpk(ftanh(acc[mt][n][2]), ftanh(acc[mt][n][3])));
    }

    f32x4 ro[4];
    #pragma unroll
    for (int n = 0; n < 4; ++n) ro[n] = f32x4{0.f, 0.f, 0.f, 0.f};

    // ---------------- 4 contexts ----------------
    #pragma unroll 1
    for (int r = 0; r < 4; ++r){
        const bool ht = (r < 3);
        uint2 tgp[4][4];
        f32x4 acc[4][4];

        if (ht){
            float xt[5];
            #pragma unroll
            for (int k = 0; k < 5; ++k) xt[k] = sp[r*18 + 13 + k];
            write_xrow<5>(XW, xt);
            zacc(acc);
            layer_k32(Ab, Bb, OF_TB1, acc);
            epi_tanh(EW, acc);
            ld_bias(WB, BTB2, q, acc);
            layer_k64(Ab, Bb, OF_TB2, acc);
            #pragma unroll
            for (int mt = 0; mt < 4; ++mt)
                #pragma unroll
                for (int n = 0; n < 4; ++n)
                    tgp[mt][n] = make_uint2(cvtpk(ftanh(acc[mt][n][0]), ftanh(acc[mt][n][1])),
                                            cvtpk(ftanh(acc[mt][n][2]), ftanh(acc[mt][n][3])));
        }

        float x14[14]; float maskf = 1.0f;
        #pragma unroll
        for (int k = 0; k < 8; ++k) x14[k] = a8[k];
        if (ht){
            x14[0] -= sp[r*18 + 0];
            x14[1] -= sp[r*18 + 1];
            #pragma unroll
            for (int k = 0; k < 6; ++k) x14[8 + k] = sp[r*18 + 3 + k];
            maskf = (x14[8] == -1.0f) ? 0.0f : 1.0f;
        } else {
            const float* tp = table + (size_t)eme*6;
            #pragma unroll
            for (int k = 0; k < 6; ++k) x14[8 + k] = tp[k];
        }
        write_xrow<14>(XW, x14);

        zacc(acc);
        layer_k32(Ab, Bb, OF_W1, acc);
        epi_tanh(EW, acc);

        ld_bias(WB, BB1B, q, acc);
        layer_k64(Ab, Bb, OF_W1B, acc);
        #pragma unroll
        for (int mt = 0; mt < 4; ++mt)                      // tanh * gate1
            #pragma unroll
            for (int n = 0; n < 4; ++n){
                const uint lo = gp[mt][n].x, hi = gp[mt][n].y;
                const float t0 = ftanh(acc[mt][n][0]) * __uint_as_float(lo << 16);
                const float t1 = ftanh(acc[mt][n][1]) * __uint_as_float(lo & 0xffff0000u);
                const float t2 = ftanh(acc[mt][n][2]) * __uint_as_float(hi << 16);
                const float t3 = ftanh(acc[mt][n][3]) * __uint_as_float(hi & 0xffff0000u);
                stD(EW, mt, n, cvtpk(t0, t1), cvtpk(t2, t3));
            }

        ld_bias(WB, BB1C, q, acc);
        layer_k64(Ab, Bb, OF_W1C, acc);
        #pragma unroll
        for (int mt = 0; mt < 4; ++mt)                      // tanh (* tg)
            #pragma unroll
            for (int n = 0; n < 4; ++n){
                float m0 = 1.f, m1 = 1.f, m2 = 1.f, m3 = 1.f;
                if (ht){
                    const uint lo = tgp[mt][n].x, hi = tgp[mt][n].y;
                    m0 = __uint_as_float(lo << 16); m1 = __uint_as_float(lo & 0xffff0000u);
                    m2 = __uint_as_float(hi << 16); m3 = __uint_as_float(hi & 0xffff0000u);
                }
                stD(EW, mt, n, cvtpk(ftanh(acc[mt][n][0])*m0, ftanh(acc[mt][n][1])*m1),
                               cvtpk(ftanh(acc[mt][n][2])*m2, ftanh(acc[mt][n][3])*m3));
            }

        // heads: rows 0..7 = v, row 8 = w-logit
        f32x4 ah[4];
        { const f32x4 b4 = *(const f32x4*)&WB[BH + 4*q];
          #pragma unroll
          for (int n = 0; n < 4; ++n) ah[n] = b4; }
        head_k64(Ab, Bb, ah);

        #pragma unroll
        for (int n = 0; n < 4; ++n){
            const float wm = fsigm(ah[n][0]);               // valid on lanes 32..47 (row 8)
            const float w  = __shfl(wm, 32 + (lane & 15), 64)
                           * __shfl(maskf, 16*n + (lane & 15), 64);
            #pragma unroll
            for (int c = 0; c < 4; ++c) ro[n][c] += w * ah[n][c];
        }
    }

    // ---------------- out = action + residuals ----------------
    if (lane < 32){
        #pragma unroll
        for (int n = 0; n < 4; ++n){
            const int e2 = ebw + 16*n + (lane & 15);
            if (e2 < Btot){
                const int co = 4*q;
                const float4 av = *(const float4*)(action + (size_t)e2*8 + co);
                float4 res;
                res.x = av.x + ro[n][0]; res.y = av.y + ro[n][1];
                res.z = av.z + ro[n][2]; res.w = av.w + ro[n][3];
                *(float4*)(out + (size_t)e2*8 + co) = res;
            }
        }
    }
}

extern "C" void kernel_launch(void* const* d_in, const int* in_sizes, int n_in,
                              void* d_out, int out_size, void* d_ws, size_t ws_size,
                              hipStream_t stream)
{
    const float* states = (const float*)d_in[0];
    const float* action = (const float*)d_in[1];
    const float* b_type = (const float*)d_in[2];
    const float* table  = (const float*)d_in[3];
    const float* W1  = (const float*)d_in[4];
    const float* b1  = (const float*)d_in[5];
    const float* W1b = (const float*)d_in[6];
    const float* b1b = (const float*)d_in[7];
    const float* W1c = (const float*)d_in[8];
    const float* b1c = (const float*)d_in[9];
    const float* W2a = (const float*)d_in[10];
    const float* b2a = (const float*)d_in[11];
    const float* W2b = (const float*)d_in[12];
    const float* b2b = (const float*)d_in[13];
    const float* Ta1 = (const float*)d_in[14];
    const float* ta1 = (const float*)d_in[15];
    const float* Ta2 = (const float*)d_in[16];
    const float* ta2 = (const float*)d_in[17];
    const float* Tb1 = (const float*)d_in[18];
    const float* tb1 = (const float*)d_in[19];
    const float* Tb2 = (const float*)d_in[20];
    const float* tb2 = (const float*)d_in[21];
    float* out = (float*)d_out;
    u16* WS = (u16*)d_ws;

    const int Btot = in_sizes[1] / 8;                  // action is (B, 8)
    prep_weights<<<dim3(5), dim3(256), 0, stream>>>(
        W1, b1, W1b, b1b, W1c, b1c, W2a, b2a, W2b, b2b,
        Ta1, ta1, Ta2, ta2, Tb1, tb1, Tb2, tb2, WS);
    const int grid = (Btot + 255) / 256;               // 4 waves/block, 64 elem/wave
    net_mfma<<<dim3(grid), dim3(256), 0, stream>>>(
        states, action, b_type, table, WS, Btot, out);
}

// Round 7
// 178.544 us; speedup vs baseline: 1.5412x; 1.5412x over previous
//
#include <hip/hip_runtime.h>

typedef unsigned int  uint;
typedef unsigned short u16;
typedef __attribute__((ext_vector_type(8))) short bf16x8;   // 8 bf16 in 4 VGPRs
typedef __attribute__((ext_vector_type(4))) float f32x4;

// ---- d_ws weight-fragment offsets (u16 units) ----
#define OF_W1B   0
#define OF_W1C   4096
#define OF_TA2   8192
#define OF_TB2   12288
#define OF_W1    16384
#define OF_TA1   18432
#define OF_TB1   20480
#define OF_W2AB  22528
#define WTOT     23552
// ---- bias offsets (f32 units, region starts at WS + WTOT u16) ----
#define BTA2 0
#define BTB2 64
#define BB1B 128
#define BB1C 192
#define BH   256   // [0..7]=b2a, [8]=b2b, [9..15]=0
#define BIASN 272

#if defined(__has_builtin) && __has_builtin(__builtin_amdgcn_exp2f)
#define EXP2F(x) __builtin_amdgcn_exp2f(x)
#else
#define EXP2F(x) __expf((x) * 0.6931471805599453f)
#endif
#if defined(__has_builtin) && __has_builtin(__builtin_amdgcn_rcpf)
#define RCPF(x) __builtin_amdgcn_rcpf(x)
#else
#define RCPF(x) __fdividef(1.0f, (x))
#endif

// tanh = 1 - 2/(exp2(x*2*log2e)+1): 3 VALU + 2 trans
__device__ __forceinline__ float ftanh(float x){
    const float e = EXP2F(x * 2.8853900817779268f);
    return __builtin_fmaf(-2.0f, RCPF(e + 1.0f), 1.0f);
}
__device__ __forceinline__ float fsigm(float x){
    return RCPF(1.0f + EXP2F(-1.4426950408889634f * x));
}
// pack 2 f32 -> 2 bf16 (RNE), 1 instruction
__device__ __forceinline__ uint cvtpk(float lo, float hi){
    uint r; asm("v_cvt_pk_bf16_f32 %0, %1, %2" : "=v"(r) : "v"(lo), "v"(hi)); return r;
}
__device__ __forceinline__ u16 bfb(float x){    // prep-kernel scalar pack
    union { float f; uint u; } v; v.f = x;
    return (u16)((v.u + 0x7fffu + ((v.u >> 16) & 1u)) >> 16);
}
__device__ __forceinline__ f32x4 MFMA(bf16x8 a, bf16x8 b, f32x4 c){
    return __builtin_amdgcn_mfma_f32_16x16x32_bf16(a, b, c, 0, 0, 0);
}

__device__ __forceinline__ void zacc(f32x4 (&acc)[4][4]){
    #pragma unroll
    for (int mt = 0; mt < 4; ++mt)
        #pragma unroll
        for (int n = 0; n < 4; ++n) acc[mt][n] = f32x4{0.f, 0.f, 0.f, 0.f};
}
__device__ __forceinline__ void ld_bias(const float* __restrict__ WB, int bb, int q,
                                        f32x4 (&acc)[4][4]){
    #pragma unroll
    for (int mt = 0; mt < 4; ++mt){
        const f32x4 b4 = *(const f32x4*)&WB[bb + 16*mt + 4*q];
        #pragma unroll
        for (int n = 0; n < 4; ++n) acc[mt][n] = b4;
    }
}

// ---- layers: Ab = &WS[lane*8] (GLOBAL, L1-hot), Bb = &ACT_wave[lane*8] (LDS) ----
__device__ __forceinline__ void layer_k32(const u16* __restrict__ Ab, const u16* Bb, int WB,
                                          f32x4 (&acc)[4][4]){
    bf16x8 A[4];
    #pragma unroll
    for (int mt = 0; mt < 4; ++mt) A[mt] = *(const bf16x8*)&Ab[WB + mt*512];
    #pragma unroll
    for (int n = 0; n < 4; ++n){
        const bf16x8 B = *(const bf16x8*)&Bb[n*1024];
        #pragma unroll
        for (int mt = 0; mt < 4; ++mt) acc[mt][n] = MFMA(A[mt], B, acc[mt][n]);
    }
}
__device__ __forceinline__ void layer_k64(const u16* __restrict__ Ab, const u16* Bb, int WB,
                                          f32x4 (&acc)[4][4]){
    #pragma unroll
    for (int s = 0; s < 2; ++s){          // s-outer: only 4 A-frags (16 VGPR) live
        bf16x8 A[4];
        #pragma unroll
        for (int mt = 0; mt < 4; ++mt) A[mt] = *(const bf16x8*)&Ab[WB + (mt*2+s)*512];
        #pragma unroll
        for (int n = 0; n < 4; ++n){
            const bf16x8 B = *(const bf16x8*)&Bb[n*1024 + s*512];
            #pragma unroll
            for (int mt = 0; mt < 4; ++mt) acc[mt][n] = MFMA(A[mt], B, acc[mt][n]);
        }
    }
}
__device__ __forceinline__ void head_k64(const u16* __restrict__ Ab, const u16* Bb,
                                         f32x4 (&ah)[4]){
    const bf16x8 A0 = *(const bf16x8*)&Ab[OF_W2AB];
    const bf16x8 A1 = *(const bf16x8*)&Ab[OF_W2AB + 512];
    #pragma unroll
    for (int n = 0; n < 4; ++n){
        const bf16x8 B0 = *(const bf16x8*)&Bb[n*1024];
        const bf16x8 B1 = *(const bf16x8*)&Bb[n*1024 + 512];
        ah[n] = MFMA(A0, B0, ah[n]);
        ah[n] = MFMA(A1, B1, ah[n]);
    }
}

// D-epilogue store: lane holds rows j=16mt+4q+c of col b=16n+(lane&15); dest = B-frag slot
__device__ __forceinline__ void stD(u16* EW, int mt, int n, uint lo, uint hi){
    *(uint2*)&EW[(n*2 + (mt>>1))*512 + (mt&1)*256] = make_uint2(lo, hi);
}
__device__ __forceinline__ void epi_tanh(u16* EW, const f32x4 (&acc)[4][4]){
    #pragma unroll
    for (int mt = 0; mt < 4; ++mt)
        #pragma unroll
        for (int n = 0; n < 4; ++n)
            stD(EW, mt, n, cvtpk(ftanh(acc[mt][n][0]), ftanh(acc[mt][n][1])),
                           cvtpk(ftanh(acc[mt][n][2]), ftanh(acc[mt][n][3])));
}

// input row write: lane's own row, k=0..31 (k31 = 1.0 -> bias-in-k31)
template<int NR>
__device__ __forceinline__ void write_xrow(u16* XW, const float (&x)[NR]){
    uint buf[16];
    #pragma unroll
    for (int i = 0; i < 16; ++i){
        if (2*i < NR){
            const float lo = x[2*i];
            const float hi = (2*i+1 < NR) ? x[2*i+1] : 0.f;
            buf[i] = cvtpk(lo, hi);
        } else buf[i] = 0u;
    }
    buf[15] = 0x3F800000u;   // k30=0, k31=bf16(1.0)
    #pragma unroll
    for (int kb = 0; kb < 4; ++kb)
        *(uint4*)&XW[kb*128] = make_uint4(buf[4*kb], buf[4*kb+1], buf[4*kb+2], buf[4*kb+3]);
}

// =================== prep kernel: weights -> fragment layout in d_ws ===================
__global__ __launch_bounds__(256)
void prep_weights(const float* __restrict__ W1,  const float* __restrict__ b1,
                  const float* __restrict__ W1b, const float* __restrict__ b1b,
                  const float* __restrict__ W1c, const float* __restrict__ b1c,
                  const float* __restrict__ W2a, const float* __restrict__ b2a,
                  const float* __restrict__ W2b, const float* __restrict__ b2b,
                  const float* __restrict__ Ta1, const float* __restrict__ ta1,
                  const float* __restrict__ Ta2, const float* __restrict__ ta2,
                  const float* __restrict__ Tb1, const float* __restrict__ tb1,
                  const float* __restrict__ Tb2, const float* __restrict__ tb2,
                  u16* __restrict__ WS)
{
    const int b = blockIdx.x, tid = threadIdx.x;
    if (b < 4){
        const float* Wg = (b==0) ? W1b : (b==1) ? W1c : (b==2) ? Ta2 : Tb2;
        const int    bb = (b==0) ? OF_W1B : (b==1) ? OF_W1C : (b==2) ? OF_TA2 : OF_TB2;
        #pragma unroll 1
        for (int idx = tid; idx < 4096; idx += 256){
            const int k = idx >> 6, j = idx & 63;   // A[j][k] = W[k][j]
            WS[bb + (((j>>4)<<1)|(k>>5))*512 + ((j&15)|(((k>>3)&3)<<4))*8 + (k&7)] = bfb(Wg[idx]);
        }
        return;
    }
    // ---- block 4: zero pads, small matrices, k31 bias rows, f32 bias table ----
    float* WB = (float*)(WS + WTOT);
    #pragma unroll 1
    for (int i = tid; i < (WTOT - OF_W1); i += 256) WS[OF_W1 + i] = 0;
    __syncthreads();
    #pragma unroll 1
    for (int idx = tid; idx < 896; idx += 256){          // W1: 14x64
        const int k = idx >> 6, j = idx & 63;
        WS[OF_W1 + (j>>4)*512 + ((j&15)|(((k>>3)&3)<<4))*8 + (k&7)] = bfb(W1[idx]);
    }
    #pragma unroll 1
    for (int idx = tid; idx < 320; idx += 256){          // Ta1 / Tb1: 5x64
        const int k = idx >> 6, j = idx & 63;
        const int d = (j>>4)*512 + ((j&15)|(((k>>3)&3)<<4))*8 + (k&7);
        WS[OF_TA1 + d] = bfb(Ta1[idx]);
        WS[OF_TB1 + d] = bfb(Tb1[idx]);
    }
    #pragma unroll 1
    for (int idx = tid; idx < 512; idx += 256){          // W2a: m=i(0..7), k=j
        const int j = idx >> 3, i = idx & 7;
        WS[OF_W2AB + (j>>5)*512 + (i|(((j>>3)&3)<<4))*8 + (j&7)] = bfb(W2a[idx]);
    }
    if (tid < 64){
        const int j = tid;
        WS[OF_W2AB + (j>>5)*512 + (8|(((j>>3)&3)<<4))*8 + (j&7)] = bfb(W2b[j]); // m=8 row
        const int d31 = ((j&15)|(3<<4))*8 + 7;           // k=31 bias rows
        WS[OF_W1  + (j>>4)*512 + d31] = bfb(b1[j]);
        WS[OF_TA1 + (j>>4)*512 + d31] = bfb(ta1[j]);
        WS[OF_TB1 + (j>>4)*512 + d31] = bfb(tb1[j]);
        WB[BTA2+j] = ta2[j]; WB[BTB2+j] = tb2[j];
        WB[BB1B+j] = b1b[j]; WB[BB1C+j] = b1c[j];
    }
    if (tid < 16) WB[BH+tid] = (tid < 8) ? b2a[tid] : (tid == 8 ? b2b[0] : 0.0f);
}

// =================== main kernel ===================
// EMPIRICAL VGPR LAW on this toolchain (R2-R5): cap = 256/min_waves_per_eu.
//   (2,2) -> 128 VGPR (R2/R3, ~9MB spill, works)
//   (4)/(4,4) -> 64 VGPR (R4/R5, 265MB spill, catastrophic)
// With 32KB LDS, occupancy is VGPR-limited: 4 waves/SIMD (512/128) = 16/CU.
// R6 failed ONLY due to the A[mt][s-s] splat typo in layer_k64 (fixed here).
__global__ __launch_bounds__(256)
__attribute__((amdgpu_waves_per_eu(2, 2)))
void net_mfma(const float* __restrict__ states, const float* __restrict__ action,
              const float* __restrict__ b_type, const float* __restrict__ table,
              const u16* __restrict__ WS, int Btot, float* __restrict__ out)
{
    __shared__ u16 ACT[4*4096];        // 32 KB: per-wave [tile n][sub s][lane][8] bf16

    const int tid  = threadIdx.x;
    const int lane = tid & 63;
    const int q    = lane >> 4;
    const int wv   = tid >> 6;
    u16* ACW = &ACT[wv << 12];
    const u16*   Ab = &WS[lane*8];                 // global, L1-hot
    const float* WB = (const float*)(WS + WTOT);   // f32 bias table
    const u16* Bb = &ACW[lane*8];
    u16* XW = &ACW[(lane>>4)*1024 + (lane&15)*8];
    u16* EW = &ACW[(q>>1)*128 + (lane&15)*8 + 4*(q&1)];

    const int ebw   = blockIdx.x*256 + wv*64;
    const int elast = Btot - 1;
    const int eme   = min(ebw + lane, elast);

    float a8[8];
    { const float* ap = action + (size_t)eme*8;
      const float4 a0 = *(const float4*)ap; const float4 a1 = *(const float4*)(ap+4);
      a8[0]=a0.x; a8[1]=a0.y; a8[2]=a0.z; a8[3]=a0.w; a8[4]=a1.x; a8[5]=a1.y; a8[6]=a1.z; a8[7]=a1.w; }
    const float* sp = states + (size_t)eme*54;

    // ---------------- gate1, packed bf16 in regs ----------------
    uint2 gp[4][4];
    {
        float x5[5];
        { const float* bp = b_type + (size_t)eme*5;
          #pragma unroll
          for (int k = 0; k < 5; ++k) x5[k] = bp[k]; }
        write_xrow<5>(XW, x5);
        f32x4 acc[4][4];
        zacc(acc);
        layer_k32(Ab, Bb, OF_TA1, acc);
        epi_tanh(EW, acc);
        ld_bias(WB, BTA2, q, acc);
        layer_k64(Ab, Bb, OF_TA2, acc);
        #pragma unroll
        for (int mt = 0; mt < 4; ++mt)
            #pragma unroll
            for (int n = 0; n < 4; ++n)
                gp[mt][n] = make_uint2(cvtpk(ftanh(acc[mt][n][0]), ftanh(acc[mt][n][1])),
                                       cvtpk(ftanh(acc[mt][n][2]), ftanh(acc[mt][n][3])));
    }

    f32x4 ro[4];
    #pragma unroll
    for (int n = 0; n < 4; ++n) ro[n] = f32x4{0.f, 0.f, 0.f, 0.f};

    // ---------------- 4 contexts ----------------
    #pragma unroll 1
    for (int r = 0; r < 4; ++r){
        const bool ht = (r < 3);
        uint2 tgp[4][4];
        f32x4 acc[4][4];

        if (ht){
            float xt[5];
            #pragma unroll
            for (int k = 0; k < 5; ++k) xt[k] = sp[r*18 + 13 + k];
            write_xrow<5>(XW, xt);
            zacc(acc);
            layer_k32(Ab, Bb, OF_TB1, acc);
            epi_tanh(EW, acc);
            ld_bias(WB, BTB2, q, acc);
            layer_k64(Ab, Bb, OF_TB2, acc);
            #pragma unroll
            for (int mt = 0; mt < 4; ++mt)
                #pragma unroll
                for (int n = 0; n < 4; ++n)
                    tgp[mt][n] = make_uint2(cvtpk(ftanh(acc[mt][n][0]), ftanh(acc[mt][n][1])),
                                            cvtpk(ftanh(acc[mt][n][2]), ftanh(acc[mt][n][3])));
        }

        float x14[14]; float maskf = 1.0f;
        #pragma unroll
        for (int k = 0; k < 8; ++k) x14[k] = a8[k];
        if (ht){
            x14[0] -= sp[r*18 + 0];
            x14[1] -= sp[r*18 + 1];
            #pragma unroll
            for (int k = 0; k < 6; ++k) x14[8 + k] = sp[r*18 + 3 + k];
            maskf = (x14[8] == -1.0f) ? 0.0f : 1.0f;
        } else {
            const float* tp = table + (size_t)eme*6;
            #pragma unroll
            for (int k = 0; k < 6; ++k) x14[8 + k] = tp[k];
        }
        write_xrow<14>(XW, x14);

        zacc(acc);
        layer_k32(Ab, Bb, OF_W1, acc);
        epi_tanh(EW, acc);

        ld_bias(WB, BB1B, q, acc);
        layer_k64(Ab, Bb, OF_W1B, acc);
        #pragma unroll
        for (int mt = 0; mt < 4; ++mt)                      // tanh * gate1
            #pragma unroll
            for (int n = 0; n < 4; ++n){
                const uint lo = gp[mt][n].x, hi = gp[mt][n].y;
                const float t0 = ftanh(acc[mt][n][0]) * __uint_as_float(lo << 16);
                const float t1 = ftanh(acc[mt][n][1]) * __uint_as_float(lo & 0xffff0000u);
                const float t2 = ftanh(acc[mt][n][2]) * __uint_as_float(hi << 16);
                const float t3 = ftanh(acc[mt][n][3]) * __uint_as_float(hi & 0xffff0000u);
                stD(EW, mt, n, cvtpk(t0, t1), cvtpk(t2, t3));
            }

        ld_bias(WB, BB1C, q, acc);
        layer_k64(Ab, Bb, OF_W1C, acc);
        #pragma unroll
        for (int mt = 0; mt < 4; ++mt)                      // tanh (* tg)
            #pragma unroll
            for (int n = 0; n < 4; ++n){
                float m0 = 1.f, m1 = 1.f, m2 = 1.f, m3 = 1.f;
                if (ht){
                    const uint lo = tgp[mt][n].x, hi = tgp[mt][n].y;
                    m0 = __uint_as_float(lo << 16); m1 = __uint_as_float(lo & 0xffff0000u);
                    m2 = __uint_as_float(hi << 16); m3 = __uint_as_float(hi & 0xffff0000u);
                }
                stD(EW, mt, n, cvtpk(ftanh(acc[mt][n][0])*m0, ftanh(acc[mt][n][1])*m1),
                               cvtpk(ftanh(acc[mt][n][2])*m2, ftanh(acc[mt][n][3])*m3));
            }

        // heads: rows 0..7 = v, row 8 = w-logit
        f32x4 ah[4];
        { const f32x4 b4 = *(const f32x4*)&WB[BH + 4*q];
          #pragma unroll
          for (int n = 0; n < 4; ++n) ah[n] = b4; }
        head_k64(Ab, Bb, ah);

        #pragma unroll
        for (int n = 0; n < 4; ++n){
            const float wm = fsigm(ah[n][0]);               // valid on lanes 32..47 (row 8)
            const float w  = __shfl(wm, 32 + (lane & 15), 64)
                           * __shfl(maskf, 16*n + (lane & 15), 64);
            #pragma unroll
            for (int c = 0; c < 4; ++c) ro[n][c] += w * ah[n][c];
        }
    }

    // ---------------- out = action + residuals ----------------
    if (lane < 32){
        #pragma unroll
        for (int n = 0; n < 4; ++n){
            const int e2 = ebw + 16*n + (lane & 15);
            if (e2 < Btot){
                const int co = 4*q;
                const float4 av = *(const float4*)(action + (size_t)e2*8 + co);
                float4 res;
                res.x = av.x + ro[n][0]; res.y = av.y + ro[n][1];
                res.z = av.z + ro[n][2]; res.w = av.w + ro[n][3];
                *(float4*)(out + (size_t)e2*8 + co) = res;
            }
        }
    }
}

extern "C" void kernel_launch(void* const* d_in, const int* in_sizes, int n_in,
                              void* d_out, int out_size, void* d_ws, size_t ws_size,
                              hipStream_t stream)
{
    const float* states = (const float*)d_in[0];
    const float* action = (const float*)d_in[1];
    const float* b_type = (const float*)d_in[2];
    const float* table  = (const float*)d_in[3];
    const float* W1  = (const float*)d_in[4];
    const float* b1  = (const float*)d_in[5];
    const float* W1b = (const float*)d_in[6];
    const float* b1b = (const float*)d_in[7];
    const float* W1c = (const float*)d_in[8];
    const float* b1c = (const float*)d_in[9];
    const float* W2a = (const float*)d_in[10];
    const float* b2a = (const float*)d_in[11];
    const float* W2b = (const float*)d_in[12];
    const float* b2b = (const float*)d_in[13];
    const float* Ta1 = (const float*)d_in[14];
    const float* ta1 = (const float*)d_in[15];
    const float* Ta2 = (const float*)d_in[16];
    const float* ta2 = (const float*)d_in[17];
    const float* Tb1 = (const float*)d_in[18];
    const float* tb1 = (const float*)d_in[19];
    const float* Tb2 = (const float*)d_in[20];
    const float* tb2 = (const float*)d_in[21];
    float* out = (float*)d_out;
    u16* WS = (u16*)d_ws;

    const int Btot = in_sizes[1] / 8;                  // action is (B, 8)
    prep_weights<<<dim3(5), dim3(256), 0, stream>>>(
        W1, b1, W1b, b1b, W1c, b1c, W2a, b2a, W2b, b2b,
        Ta1, ta1, Ta2, ta2, Tb1, tb1, Tb2, tb2, WS);
    const int grid = (Btot + 255) / 256;               // 4 waves/block, 64 elem/wave
    net_mfma<<<dim3(grid), dim3(256), 0, stream>>>(
        states, action, b_type, table, WS, Btot, out);
}

// Round 8
// 142.939 us; speedup vs baseline: 1.9250x; 1.2491x over previous
//
#include <hip/hip_runtime.h>

typedef unsigned int  uint;
typedef unsigned short u16;
typedef __attribute__((ext_vector_type(8))) short bf16x8;   // 8 bf16 in 4 VGPRs
typedef __attribute__((ext_vector_type(4))) float f32x4;

// ---- d_ws weight-fragment offsets (u16 units) ----
// First 4 matrices (K=64 path) are copied to LDS per block; rest read from global.
#define OF_W1B   0
#define OF_W1C   4096
#define OF_TA2   8192
#define OF_TB2   12288
#define SHW_U16  16384      // LDS-resident portion: 32 KB
#define OF_W1    16384
#define OF_TA1   18432
#define OF_TB1   20480
#define OF_W2AB  22528
#define WTOT     23552
// ---- bias offsets (f32 units, region starts at WS + WTOT u16) ----
#define BTA2 0
#define BTB2 64
#define BB1B 128
#define BB1C 192
#define BH   256   // [0..7]=b2a, [8]=b2b, [9..15]=0
#define BIASN 272

#if defined(__has_builtin) && __has_builtin(__builtin_amdgcn_exp2f)
#define EXP2F(x) __builtin_amdgcn_exp2f(x)
#else
#define EXP2F(x) __expf((x) * 0.6931471805599453f)
#endif
#if defined(__has_builtin) && __has_builtin(__builtin_amdgcn_rcpf)
#define RCPF(x) __builtin_amdgcn_rcpf(x)
#else
#define RCPF(x) __fdividef(1.0f, (x))
#endif

// tanh = 1 - 2/(exp2(x*2*log2e)+1): 3 VALU + 2 trans
__device__ __forceinline__ float ftanh(float x){
    const float e = EXP2F(x * 2.8853900817779268f);
    return __builtin_fmaf(-2.0f, RCPF(e + 1.0f), 1.0f);
}
__device__ __forceinline__ float fsigm(float x){
    return RCPF(1.0f + EXP2F(-1.4426950408889634f * x));
}
__device__ __forceinline__ uint cvtpk(float lo, float hi){
    uint r; asm("v_cvt_pk_bf16_f32 %0, %1, %2" : "=v"(r) : "v"(lo), "v"(hi)); return r;
}
__device__ __forceinline__ u16 bfb(float x){    // prep-kernel scalar pack
    union { float f; uint u; } v; v.f = x;
    return (u16)((v.u + 0x7fffu + ((v.u >> 16) & 1u)) >> 16);
}
__device__ __forceinline__ f32x4 MFMA(bf16x8 a, bf16x8 b, f32x4 c){
    return __builtin_amdgcn_mfma_f32_16x16x32_bf16(a, b, c, 0, 0, 0);
}

// ================== N=32 per wave: acc[4 mt][2 n], ACT 4KB/wave ==================
__device__ __forceinline__ void zacc(f32x4 (&acc)[4][2]){
    #pragma unroll
    for (int mt = 0; mt < 4; ++mt)
        #pragma unroll
        for (int n = 0; n < 2; ++n) acc[mt][n] = f32x4{0.f, 0.f, 0.f, 0.f};
}
__device__ __forceinline__ void ld_bias(const float* SB, int bb, int q, f32x4 (&acc)[4][2]){
    #pragma unroll
    for (int mt = 0; mt < 4; ++mt){
        const f32x4 b4 = *(const f32x4*)&SB[bb + 16*mt + 4*q];
        acc[mt][0] = b4; acc[mt][1] = b4;
    }
}

// K=32 layer: A-frags from GLOBAL (L1-hot small matrices), B from wave ACT (LDS)
__device__ __forceinline__ void layer_k32(const u16* __restrict__ AbG, const u16* Bb, int WB,
                                          f32x4 (&acc)[4][2]){
    bf16x8 A[4];
    #pragma unroll
    for (int mt = 0; mt < 4; ++mt) A[mt] = *(const bf16x8*)&AbG[WB + mt*512];
    #pragma unroll
    for (int n = 0; n < 2; ++n){
        const bf16x8 B = *(const bf16x8*)&Bb[n*1024];
        #pragma unroll
        for (int mt = 0; mt < 4; ++mt) acc[mt][n] = MFMA(A[mt], B, acc[mt][n]);
    }
}
// K=64 layer: A-frags from LDS SHW, B from wave ACT
__device__ __forceinline__ void layer_k64(const u16* AbL, const u16* Bb, int WB,
                                          f32x4 (&acc)[4][2]){
    #pragma unroll
    for (int s = 0; s < 2; ++s){
        bf16x8 A[4];
        #pragma unroll
        for (int mt = 0; mt < 4; ++mt) A[mt] = *(const bf16x8*)&AbL[WB + (mt*2+s)*512];
        #pragma unroll
        for (int n = 0; n < 2; ++n){
            const bf16x8 B = *(const bf16x8*)&Bb[n*1024 + s*512];
            #pragma unroll
            for (int mt = 0; mt < 4; ++mt) acc[mt][n] = MFMA(A[mt], B, acc[mt][n]);
        }
    }
}
__device__ __forceinline__ void head_k64(const u16* __restrict__ AbG, const u16* Bb,
                                         f32x4 (&ah)[2]){
    const bf16x8 A0 = *(const bf16x8*)&AbG[OF_W2AB];
    const bf16x8 A1 = *(const bf16x8*)&AbG[OF_W2AB + 512];
    #pragma unroll
    for (int n = 0; n < 2; ++n){
        const bf16x8 B0 = *(const bf16x8*)&Bb[n*1024];
        const bf16x8 B1 = *(const bf16x8*)&Bb[n*1024 + 512];
        ah[n] = MFMA(A0, B0, ah[n]);
        ah[n] = MFMA(A1, B1, ah[n]);
    }
}

// D-epilogue store: lane holds rows j=16mt+4q+c of element-col 16n+(lane&15);
// dest = next layer's B-frag slot. EW = &ACW[(q>>1)*128 + (lane&15)*8 + 4*(q&1)]
__device__ __forceinline__ void stD(u16* EW, int mt, int n, uint lo, uint hi){
    *(uint2*)&EW[(n*2 + (mt>>1))*512 + (mt&1)*256] = make_uint2(lo, hi);
}
__device__ __forceinline__ void epi_tanh(u16* EW, const f32x4 (&acc)[4][2]){
    #pragma unroll
    for (int mt = 0; mt < 4; ++mt)
        #pragma unroll
        for (int n = 0; n < 2; ++n)
            stD(EW, mt, n, cvtpk(ftanh(acc[mt][n][0]), ftanh(acc[mt][n][1])),
                           cvtpk(ftanh(acc[mt][n][2]), ftanh(acc[mt][n][3])));
}

// input row write, element c=lane&31: k=0..31, k31=1.0 (bias-in-k31).
// half h=lane>>5 writes k-groups g=2h, 2h+1 -> all 64 lanes busy, region covered once.
template<int NR>
__device__ __forceinline__ void write_xrow(u16* ACW, int lane, const float (&x)[NR]){
    uint buf[16];
    #pragma unroll
    for (int i = 0; i < 16; ++i){
        if (2*i < NR){
            const float lo = x[2*i];
            const float hi = (2*i+1 < NR) ? x[2*i+1] : 0.f;
            buf[i] = cvtpk(lo, hi);
        } else buf[i] = 0u;
    }
    buf[15] = 0x3F800000u;   // k30=0, k31=bf16(1.0)
    const int c = lane & 31, n = c >> 4, col = c & 15, h = lane >> 5;
    #pragma unroll
    for (int gg = 0; gg < 2; ++gg){
        const int g = 2*h + gg;
        *(uint4*)&ACW[n*1024 + (g*16 + col)*8] =
            make_uint4(buf[4*g], buf[4*g+1], buf[4*g+2], buf[4*g+3]);
    }
}

// =================== prep kernel: weights -> fragment layout in d_ws ===================
__global__ __launch_bounds__(256)
void prep_weights(const float* __restrict__ W1,  const float* __restrict__ b1,
                  const float* __restrict__ W1b, const float* __restrict__ b1b,
                  const float* __restrict__ W1c, const float* __restrict__ b1c,
                  const float* __restrict__ W2a, const float* __restrict__ b2a,
                  const float* __restrict__ W2b, const float* __restrict__ b2b,
                  const float* __restrict__ Ta1, const float* __restrict__ ta1,
                  const float* __restrict__ Ta2, const float* __restrict__ ta2,
                  const float* __restrict__ Tb1, const float* __restrict__ tb1,
                  const float* __restrict__ Tb2, const float* __restrict__ tb2,
                  u16* __restrict__ WS)
{
    const int b = blockIdx.x, tid = threadIdx.x;
    if (b < 4){
        const float* Wg = (b==0) ? W1b : (b==1) ? W1c : (b==2) ? Ta2 : Tb2;
        const int    bb = (b==0) ? OF_W1B : (b==1) ? OF_W1C : (b==2) ? OF_TA2 : OF_TB2;
        #pragma unroll 1
        for (int idx = tid; idx < 4096; idx += 256){
            const int k = idx >> 6, j = idx & 63;   // A[j][k] = W[k][j]
            WS[bb + (((j>>4)<<1)|(k>>5))*512 + ((j&15)|(((k>>3)&3)<<4))*8 + (k&7)] = bfb(Wg[idx]);
        }
        return;
    }
    // ---- block 4: zero pads, small matrices, k31 bias rows, f32 bias table ----
    float* WB = (float*)(WS + WTOT);
    #pragma unroll 1
    for (int i = tid; i < (WTOT - OF_W1); i += 256) WS[OF_W1 + i] = 0;
    __syncthreads();
    #pragma unroll 1
    for (int idx = tid; idx < 896; idx += 256){          // W1: 14x64
        const int k = idx >> 6, j = idx & 63;
        WS[OF_W1 + (j>>4)*512 + ((j&15)|(((k>>3)&3)<<4))*8 + (k&7)] = bfb(W1[idx]);
    }
    #pragma unroll 1
    for (int idx = tid; idx < 320; idx += 256){          // Ta1 / Tb1: 5x64
        const int k = idx >> 6, j = idx & 63;
        const int d = (j>>4)*512 + ((j&15)|(((k>>3)&3)<<4))*8 + (k&7);
        WS[OF_TA1 + d] = bfb(Ta1[idx]);
        WS[OF_TB1 + d] = bfb(Tb1[idx]);
    }
    #pragma unroll 1
    for (int idx = tid; idx < 512; idx += 256){          // W2a: m=i(0..7), k=j
        const int j = idx >> 3, i = idx & 7;
        WS[OF_W2AB + (j>>5)*512 + (i|(((j>>3)&3)<<4))*8 + (j&7)] = bfb(W2a[idx]);
    }
    if (tid < 64){
        const int j = tid;
        WS[OF_W2AB + (j>>5)*512 + (8|(((j>>3)&3)<<4))*8 + (j&7)] = bfb(W2b[j]); // m=8 row
        const int d31 = ((j&15)|(3<<4))*8 + 7;           // k=31 bias rows
        WS[OF_W1  + (j>>4)*512 + d31] = bfb(b1[j]);
        WS[OF_TA1 + (j>>4)*512 + d31] = bfb(ta1[j]);
        WS[OF_TB1 + (j>>4)*512 + d31] = bfb(tb1[j]);
        WB[BTA2+j] = ta2[j]; WB[BTB2+j] = tb2[j];
        WB[BB1B+j] = b1b[j]; WB[BB1C+j] = b1c[j];
    }
    if (tid < 16) WB[BH+tid] = (tid < 8) ? b2a[tid] : (tid == 8 ? b2b[0] : 0.0f);
}

// =================== main kernel ===================
// REGISTER LAW (R2-R7): unified VGPR+AGPR budget = 512/min_waves_per_eu, split
// between arch and acc. (2,2)->arch 128, total 256 -> 2 waves/SIMD HARD (R7:
// occupancy 21% even at 32KB LDS). To get 3 waves/SIMD the kernel must fit
// ~170 total: this version halves per-wave tiles (N=32) so arch demand ~90,
// acc demand ~40. LDS/block ~50KB -> 3 blocks/CU matches 3 waves/SIMD.
__global__ __launch_bounds__(256)
__attribute__((amdgpu_waves_per_eu(3, 3)))
void net_mfma(const float* __restrict__ states, const float* __restrict__ action,
              const float* __restrict__ b_type, const float* __restrict__ table,
              const u16* __restrict__ WS, int Btot, float* __restrict__ out)
{
    __shared__ u16   SHW[SHW_U16];     // 32 KB: the 4 K=64 matrices, frag layout
    __shared__ float SBIAS[BIASN];     // 1 KB
    __shared__ u16   ACT[4*2048];      // 16 KB: per-wave [n][s][lane][8], N=32

    const int tid  = threadIdx.x;
    const int lane = tid & 63;
    const int q    = lane >> 4;
    const int wv   = tid >> 6;

    // ---- linear LDS staging (conflict-free uint4 copy) ----
    {
        const uint4* src = (const uint4*)WS;         // first 32 KB of WS
        uint4* dst = (uint4*)SHW;
        #pragma unroll 1
        for (int i = tid; i < SHW_U16/8; i += 256) dst[i] = src[i];
        const float* bg = (const float*)(WS + WTOT);
        #pragma unroll 1
        for (int i = tid; i < BIASN; i += 256) SBIAS[i] = bg[i];
    }
    __syncthreads();

    u16* ACW = &ACT[wv << 11];                      // 2048 u16 per wave
    const u16* AbG = &WS[lane*8];                   // global A-frags (small mats)
    const u16* AbL = &SHW[lane*8];                  // LDS A-frags (K=64 mats)
    const u16* Bb  = &ACW[lane*8];
    u16* EW = &ACW[(q>>1)*128 + (lane&15)*8 + 4*(q&1)];

    const int ebw   = blockIdx.x*128 + wv*32;       // wave's element base (N=32)
    const int elast = Btot - 1;
    const int eme   = min(ebw + (lane & 31), elast);

    float a8[8];
    { const float* ap = action + (size_t)eme*8;
      const float4 a0 = *(const float4*)ap; const float4 a1 = *(const float4*)(ap+4);
      a8[0]=a0.x; a8[1]=a0.y; a8[2]=a0.z; a8[3]=a0.w; a8[4]=a1.x; a8[5]=a1.y; a8[6]=a1.z; a8[7]=a1.w; }
    const float* sp = states + (size_t)eme*54;

    // ---------------- gate1, packed bf16 in regs ----------------
    uint2 gp[4][2];
    {
        float x5[5];
        { const float* bp = b_type + (size_t)eme*5;
          #pragma unroll
          for (int k = 0; k < 5; ++k) x5[k] = bp[k]; }
        write_xrow<5>(ACW, lane, x5);
        f32x4 acc[4][2];
        zacc(acc);
        layer_k32(AbG, Bb, OF_TA1, acc);
        epi_tanh(EW, acc);
        ld_bias(SBIAS, BTA2, q, acc);
        layer_k64(AbL, Bb, OF_TA2, acc);
        #pragma unroll
        for (int mt = 0; mt < 4; ++mt)
            #pragma unroll
            for (int n = 0; n < 2; ++n)
                gp[mt][n] = make_uint2(cvtpk(ftanh(acc[mt][n][0]), ftanh(acc[mt][n][1])),
                                       cvtpk(ftanh(acc[mt][n][2]), ftanh(acc[mt][n][3])));
    }

    f32x4 ro[2];
    ro[0] = f32x4{0.f,0.f,0.f,0.f}; ro[1] = f32x4{0.f,0.f,0.f,0.f};

    // ---------------- 4 contexts ----------------
    #pragma unroll 1
    for (int r = 0; r < 4; ++r){
        const bool ht = (r < 3);
        uint2 tgp[4][2];
        f32x4 acc[4][2];

        if (ht){
            float xt[5];
            #pragma unroll
            for (int k = 0; k < 5; ++k) xt[k] = sp[r*18 + 13 + k];
            write_xrow<5>(ACW, lane, xt);
            zacc(acc);
            layer_k32(AbG, Bb, OF_TB1, acc);
            epi_tanh(EW, acc);
            ld_bias(SBIAS, BTB2, q, acc);
            layer_k64(AbL, Bb, OF_TB2, acc);
            #pragma unroll
            for (int mt = 0; mt < 4; ++mt)
                #pragma unroll
                for (int n = 0; n < 2; ++n)
                    tgp[mt][n] = make_uint2(cvtpk(ftanh(acc[mt][n][0]), ftanh(acc[mt][n][1])),
                                            cvtpk(ftanh(acc[mt][n][2]), ftanh(acc[mt][n][3])));
        }

        float x14[14]; float maskf = 1.0f;
        #pragma unroll
        for (int k = 0; k < 8; ++k) x14[k] = a8[k];
        if (ht){
            x14[0] -= sp[r*18 + 0];
            x14[1] -= sp[r*18 + 1];
            #pragma unroll
            for (int k = 0; k < 6; ++k) x14[8 + k] = sp[r*18 + 3 + k];
            maskf = (x14[8] == -1.0f) ? 0.0f : 1.0f;
        } else {
            const float* tp = table + (size_t)eme*6;
            #pragma unroll
            for (int k = 0; k < 6; ++k) x14[8 + k] = tp[k];
        }
        write_xrow<14>(ACW, lane, x14);

        zacc(acc);
        layer_k32(AbG, Bb, OF_W1, acc);
        epi_tanh(EW, acc);

        ld_bias(SBIAS, BB1B, q, acc);
        layer_k64(AbL, Bb, OF_W1B, acc);
        #pragma unroll
        for (int mt = 0; mt < 4; ++mt)                      // tanh * gate1
            #pragma unroll
            for (int n = 0; n < 2; ++n){
                const uint lo = gp[mt][n].x, hi = gp[mt][n].y;
                const float t0 = ftanh(acc[mt][n][0]) * __uint_as_float(lo << 16);
                const float t1 = ftanh(acc[mt][n][1]) * __uint_as_float(lo & 0xffff0000u);
                const float t2 = ftanh(acc[mt][n][2]) * __uint_as_float(hi << 16);
                const float t3 = ftanh(acc[mt][n][3]) * __uint_as_float(hi & 0xffff0000u);
                stD(EW, mt, n, cvtpk(t0, t1), cvtpk(t2, t3));
            }

        ld_bias(SBIAS, BB1C, q, acc);
        layer_k64(AbL, Bb, OF_W1C, acc);
        #pragma unroll
        for (int mt = 0; mt < 4; ++mt)                      // tanh (* tg)
            #pragma unroll
            for (int n = 0; n < 2; ++n){
                float m0 = 1.f, m1 = 1.f, m2 = 1.f, m3 = 1.f;
                if (ht){
                    const uint lo = tgp[mt][n].x, hi = tgp[mt][n].y;
                    m0 = __uint_as_float(lo << 16); m1 = __uint_as_float(lo & 0xffff0000u);
                    m2 = __uint_as_float(hi << 16); m3 = __uint_as_float(hi & 0xffff0000u);
                }
                stD(EW, mt, n, cvtpk(ftanh(acc[mt][n][0])*m0, ftanh(acc[mt][n][1])*m1),
                               cvtpk(ftanh(acc[mt][n][2])*m2, ftanh(acc[mt][n][3])*m3));
            }

        // heads: rows 0..7 = v, row 8 = w-logit
        f32x4 ah[2];
        { const f32x4 b4 = *(const f32x4*)&SBIAS[BH + 4*q];
          ah[0] = b4; ah[1] = b4; }
        head_k64(AbG, Bb, ah);

        #pragma unroll
        for (int n = 0; n < 2; ++n){
            const float wm = fsigm(ah[n][0]);               // valid on lanes 32..47 (row 8)
            const float w  = __shfl(wm, 32 + (lane & 15), 64)
                           * __shfl(maskf, 16*n + (lane & 15), 64);
            #pragma unroll
            for (int c = 0; c < 4; ++c) ro[n][c] += w * ah[n][c];
        }
    }

    // ---------------- out = action + residuals ----------------
    if (lane < 32){
        #pragma unroll
        for (int n = 0; n < 2; ++n){
            const int e2 = ebw + 16*n + (lane & 15);
            if (e2 < Btot){
                const int co = 4*q;                          // q in {0,1}: cols 0..7
                const float4 av = *(const float4*)(action + (size_t)e2*8 + co);
                float4 res;
                res.x = av.x + ro[n][0]; res.y = av.y + ro[n][1];
                res.z = av.z + ro[n][2]; res.w = av.w + ro[n][3];
                *(float4*)(out + (size_t)e2*8 + co) = res;
            }
        }
    }
}

extern "C" void kernel_launch(void* const* d_in, const int* in_sizes, int n_in,
                              void* d_out, int out_size, void* d_ws, size_t ws_size,
                              hipStream_t stream)
{
    const float* states = (const float*)d_in[0];
    const float* action = (const float*)d_in[1];
    const float* b_type = (const float*)d_in[2];
    const float* table  = (const float*)d_in[3];
    const float* W1  = (const float*)d_in[4];
    const float* b1  = (const float*)d_in[5];
    const float* W1b = (const float*)d_in[6];
    const float* b1b = (const float*)d_in[7];
    const float* W1c = (const float*)d_in[8];
    const float* b1c = (const float*)d_in[9];
    const float* W2a = (const float*)d_in[10];
    const float* b2a = (const float*)d_in[11];
    const float* W2b = (const float*)d_in[12];
    const float* b2b = (const float*)d_in[13];
    const float* Ta1 = (const float*)d_in[14];
    const float* ta1 = (const float*)d_in[15];
    const float* Ta2 = (const float*)d_in[16];
    const float* ta2 = (const float*)d_in[17];
    const float* Tb1 = (const float*)d_in[18];
    const float* tb1 = (const float*)d_in[19];
    const float* Tb2 = (const float*)d_in[20];
    const float* tb2 = (const float*)d_in[21];
    float* out = (float*)d_out;
    u16* WS = (u16*)d_ws;

    const int Btot = in_sizes[1] / 8;                  // action is (B, 8)
    prep_weights<<<dim3(5), dim3(256), 0, stream>>>(
        W1, b1, W1b, b1b, W1c, b1c, W2a, b2a, W2b, b2b,
        Ta1, ta1, Ta2, ta2, Tb1, tb1, Tb2, tb2, WS);
    const int grid = (Btot + 127) / 128;               // 4 waves/block, 32 elem/wave
    net_mfma<<<dim3(grid), dim3(256), 0, stream>>>(
        states, action, b_type, table, WS, Btot, out);
}